// Round 1
// 93.393 us; speedup vs baseline: 1.0032x; 1.0032x over previous
//
#include <hip/hip_runtime.h>
#include <math.h>

#define V_SZ 100000
#define D_SZ 64
#define B_SZ 4096
#define L_SZ 50
#define K_SZ 3
#define MAX_NORM 20.0f

// Kernel 1: renorm + int8-quantize (per-row scale) into ws.
// Layout in ws: tab8[V][64] (6.4 MB) followed by float invscale[V] (400 KB).
// Memory-bound (L3-resident read, ~2 us) -- unchanged.
__global__ __launch_bounds__(256) void renorm_int8_kernel(
    const float* __restrict__ emb, unsigned char* __restrict__ tab8,
    float* __restrict__ invscale) {
    int row = blockIdx.x * 16 + (threadIdx.x >> 4);
    int m = threadIdx.x & 15;
    if (row >= V_SZ) return;
    const float4* row4 = (const float4*)(emb + (long)row * D_SZ);
    float4 v = row4[m];
    float ss = v.x * v.x + v.y * v.y + v.z * v.z + v.w * v.w;
    float mx = fmaxf(fmaxf(fabsf(v.x), fabsf(v.y)), fmaxf(fabsf(v.z), fabsf(v.w)));
    #pragma unroll
    for (int off = 1; off <= 8; off <<= 1) {
        ss += __shfl_xor(ss, off, 16);
        mx = fmaxf(mx, __shfl_xor(mx, off, 16));
    }
    float n = sqrtf(ss);
    float s = (n > MAX_NORM) ? (MAX_NORM / n) : 1.0f;   // renorm factor
    float rowmax = fmaxf(s * mx, 1e-20f);
    float qs = 127.0f / rowmax;
    int q0 = (int)rintf(s * v.x * qs) + 128;
    int q1 = (int)rintf(s * v.y * qs) + 128;
    int q2 = (int)rintf(s * v.z * qs) + 128;
    int q3 = (int)rintf(s * v.w * qs) + 128;
    unsigned int packed = (unsigned int)(q0 & 0xff) |
                          ((unsigned int)(q1 & 0xff) << 8) |
                          ((unsigned int)(q2 & 0xff) << 16) |
                          ((unsigned int)(q3 & 0xff) << 24);
    ((unsigned int*)(tab8 + (long)row * D_SZ))[m] = packed;
    if (m == 0) invscale[row] = rowmax / 127.0f;
}

// Kernel 2: one wave64 per bag; 8 tokens per iteration.
// lane = g*8 + m: g in [0,8) = token sub-slot, m in [0,8) = 8B (int2) chunk
// of the 64B int8 row -> 7 iterations cover j=0..55; j>=50 masked by sc=0.
// Zero-point hoisted: acc_d = sum_j s_j*u_jd ; result_d = acc_d - 128*sum_j s_j.
// Inner op is v_cvt_f32_ubyteN + v_fmac_f32 (2 VALU/byte, was 3).
__global__ __launch_bounds__(256) void embed_bag_int8_kernel(
    const unsigned char* __restrict__ tab8, const float* __restrict__ invscale,
    const int* __restrict__ tl, const int* __restrict__ tr,
    const int* __restrict__ tn, float* __restrict__ out) {
    const int NBAGS = B_SZ * (2 + K_SZ);
    int wave = (int)((blockIdx.x * (unsigned)blockDim.x + threadIdx.x) >> 6);
    int lane = threadIdx.x & 63;
    if (wave >= NBAGS) return;

    const int* tok;
    if (wave < B_SZ)            tok = tl + (long)wave * L_SZ;
    else if (wave < 2 * B_SZ)   tok = tr + (long)(wave - B_SZ) * L_SZ;
    else                        tok = tn + (long)(wave - 2 * B_SZ) * L_SZ;

    int   t  = (lane < L_SZ) ? tok[lane] : 0;
    float sc = (lane < L_SZ) ? invscale[t] : 0.0f;   // 0 masks junk slots 50..55

    int m = lane & 7;        // 8B chunk of the row -> dims 8m..8m+7
    int g = lane >> 3;       // token sub-slot

    float acc[8];
    #pragma unroll
    for (int d = 0; d < 8; ++d) acc[d] = 0.0f;
    float ssum = 0.0f;       // sum of per-token scales (for hoisted zero-point)

    #pragma unroll
    for (int i = 0; i < 7; ++i) {
        int j = i * 8 + g;
        int   tj = __shfl(t, j, 64);                 // all lanes active
        float sj = __shfl(sc, j, 64);
        int2 u = ((const int2*)(tab8 + (long)tj * D_SZ))[m];
        unsigned int a = (unsigned int)u.x, b = (unsigned int)u.y;
        ssum += sj;
        acc[0] = fmaf(sj, (float)( a         & 0xffu), acc[0]);
        acc[1] = fmaf(sj, (float)((a >> 8 )  & 0xffu), acc[1]);
        acc[2] = fmaf(sj, (float)((a >> 16)  & 0xffu), acc[2]);
        acc[3] = fmaf(sj, (float)( a >> 24         ),  acc[3]);
        acc[4] = fmaf(sj, (float)( b         & 0xffu), acc[4]);
        acc[5] = fmaf(sj, (float)((b >> 8 )  & 0xffu), acc[5]);
        acc[6] = fmaf(sj, (float)((b >> 16)  & 0xffu), acc[6]);
        acc[7] = fmaf(sj, (float)( b >> 24         ),  acc[7]);
    }

    // sum the 8 token sub-slots: xor-butterfly over lane bits 3..5
    #pragma unroll
    for (int off = 8; off <= 32; off <<= 1) {
        ssum += __shfl_xor(ssum, off, 64);
        #pragma unroll
        for (int d = 0; d < 8; ++d)
            acc[d] += __shfl_xor(acc[d], off, 64);
    }
    if (g == 0) {
        float bias = 128.0f * ssum;                  // hoisted zero-point
        float4* o = (float4*)(out + (long)wave * D_SZ + m * 8);
        o[0] = make_float4(acc[0] - bias, acc[1] - bias,
                           acc[2] - bias, acc[3] - bias);
        o[1] = make_float4(acc[4] - bias, acc[5] - bias,
                           acc[6] - bias, acc[7] - bias);
    }
}

extern "C" void kernel_launch(void* const* d_in, const int* in_sizes, int n_in,
                              void* d_out, int out_size, void* d_ws, size_t ws_size,
                              hipStream_t stream) {
    const float* emb = (const float*)d_in[0];
    const int* tl = (const int*)d_in[1];
    const int* tr = (const int*)d_in[2];
    const int* tn = (const int*)d_in[3];
    float* out = (float*)d_out;

    unsigned char* tab8 = (unsigned char*)d_ws;               // 6.4 MB
    float* invscale = (float*)(tab8 + (long)V_SZ * D_SZ);     // +400 KB

    renorm_int8_kernel<<<(V_SZ + 15) / 16, 256, 0, stream>>>(emb, tab8, invscale);

    const int NBAGS = B_SZ * (2 + K_SZ);            // 20480 bags = waves
    int grid = NBAGS / 4;                           // 4 waves per 256-thr block
    embed_bag_int8_kernel<<<grid, 256, 0, stream>>>(tab8, invscale, tl, tr, tn, out);
}